// Round 1
// baseline (727.839 us; speedup 1.0000x reference)
//
#include <hip/hip_runtime.h>
#include <hip/hip_bf16.h>
#include <stdint.h>

// Problem constants
#define MM   32768   // B*S
#define FFD  1024    // F
#define NQKV 3072    // 3*F

typedef __bf16 bf16x8 __attribute__((ext_vector_type(8)));
typedef float  f32x4  __attribute__((ext_vector_type(4)));

__device__ __forceinline__ unsigned short f2bf_bits(float f){
  __hip_bfloat16 h = __float2bfloat16(f);
  unsigned short u;
  __builtin_memcpy(&u, &h, 2);
  return u;
}

__device__ __forceinline__ float bf2f(unsigned short u){
  unsigned int w = ((unsigned int)u) << 16;
  float f;
  __builtin_memcpy(&f, &w, 4);
  return f;
}

__device__ __forceinline__ void gld16(const void* g, void* l){
  const unsigned int* gu = (const unsigned int*)g;
  unsigned int* lu = (unsigned int*)l;
  __builtin_amdgcn_global_load_lds(
      (const __attribute__((address_space(1))) unsigned int*)gu,
      (__attribute__((address_space(3))) unsigned int*)lu,
      16, 0, 0);
}

// ---------- convert fp32 -> bf16, 4 elems/thread ----------
__global__ __launch_bounds__(256) void k_convert_bf16(const float* __restrict__ in,
                                                      unsigned short* __restrict__ out,
                                                      int n4){
  int i = blockIdx.x * 256 + threadIdx.x;
  if (i >= n4) return;
  float4 v = ((const float4*)in)[i];
  ushort4 r;
  r.x = f2bf_bits(v.x); r.y = f2bf_bits(v.y);
  r.z = f2bf_bits(v.z); r.w = f2bf_bits(v.w);
  ((ushort4*)out)[i] = r;
}

// ---------- transpose-convert: out(N x K bf16) = in(K x N fp32)^T ----------
__global__ __launch_bounds__(256) void k_transpose_bf16(const float* __restrict__ in,
                                                        unsigned short* __restrict__ out,
                                                        int rows, int cols){
  __shared__ float tile[32][33];
  int bc = blockIdx.x * 32, br = blockIdx.y * 32;
  int tx = threadIdx.x, ty = threadIdx.y;
  #pragma unroll
  for (int j = 0; j < 32; j += 8)
    tile[ty + j][tx] = in[(size_t)(br + ty + j) * cols + bc + tx];
  __syncthreads();
  #pragma unroll
  for (int j = 0; j < 32; j += 8)
    out[(size_t)(bc + ty + j) * rows + br + tx] = f2bf_bits(tile[tx][ty + j]);
}

// ---------- bf16 MFMA GEMM: C(MxN) = A(MxK) * Bt(NxK)^T + bias ----------
// 128x128 block tile, 256 threads (4 waves in 2x2), 16x16x32 MFMA, BK=32.
template <bool BF16OUT>
__global__ __launch_bounds__(256) void k_gemm_bt(
    const unsigned short* __restrict__ A,
    const unsigned short* __restrict__ Bt,
    const float* __restrict__ b0, const float* __restrict__ b1, const float* __restrict__ b2,
    void* __restrict__ Cout, int M, int N, int K)
{
  __shared__ unsigned short As[128 * 32];
  __shared__ unsigned short Bs[128 * 32];

  const int tid  = threadIdx.x;
  const int lane = tid & 63;
  const int wave = tid >> 6;
  const int wr = wave >> 1, wc = wave & 1;
  const int quad = lane >> 4, lrow = lane & 15;

  const long rowBase = (long)blockIdx.y * 128;
  const long colBase = (long)blockIdx.x * 128;

  f32x4 acc[4][4];
  #pragma unroll
  for (int i = 0; i < 4; i++)
    #pragma unroll
    for (int j = 0; j < 4; j++)
      acc[i][j] = (f32x4){0.f, 0.f, 0.f, 0.f};

  // staging pointers: thread t loads 16B at (row = t>>2, kchunk = t&3)
  const unsigned short* ga = A  + (rowBase + (tid >> 2)) * (long)K + (tid & 3) * 8;
  const unsigned short* gb = Bt + (colBase + (tid >> 2)) * (long)K + (tid & 3) * 8;
  unsigned short* la = As + tid * 8;
  unsigned short* lb = Bs + tid * 8;
  const long rstep = 64L * K;  // 64 rows, in elements

  const int nk = K >> 5;
  for (int kt = 0; kt < nk; kt++){
    __syncthreads();                 // previous tile's reads done
    gld16(ga,         la);
    gld16(ga + rstep, la + 2048);
    gld16(gb,         lb);
    gld16(gb + rstep, lb + 2048);
    __syncthreads();                 // loads landed (vmcnt drain at barrier)

    bf16x8 af[4], bfr[4];
    #pragma unroll
    for (int i = 0; i < 4; i++)
      af[i]  = *(const bf16x8*)(As + (wr * 64 + i * 16 + lrow) * 32 + quad * 8);
    #pragma unroll
    for (int j = 0; j < 4; j++)
      bfr[j] = *(const bf16x8*)(Bs + (wc * 64 + j * 16 + lrow) * 32 + quad * 8);

    #pragma unroll
    for (int i = 0; i < 4; i++)
      #pragma unroll
      for (int j = 0; j < 4; j++)
        acc[i][j] = __builtin_amdgcn_mfma_f32_16x16x32_bf16(af[i], bfr[j], acc[i][j], 0, 0, 0);

    ga += 32; gb += 32;
  }

  // epilogue: C/D layout col = lane&15, row = quad*4 + r
  #pragma unroll
  for (int j = 0; j < 4; j++){
    long col = colBase + wc * 64 + j * 16 + lrow;
    const float* bp = (col < 1024) ? b0 : ((col < 2048) ? b1 : b2);
    float bias = bp[col & 1023];
    #pragma unroll
    for (int i = 0; i < 4; i++){
      long row0 = rowBase + wr * 64 + i * 16 + quad * 4;
      #pragma unroll
      for (int r = 0; r < 4; r++){
        float v = acc[i][j][r] + bias;
        if constexpr (BF16OUT)
          ((unsigned short*)Cout)[(row0 + r) * (long)N + col] = f2bf_bits(v);
        else
          ((float*)Cout)[(row0 + r) * (long)N + col] = v;
      }
    }
  }
}

// ---------- per-position head-attention ----------
// One wave per position (4 per block). qkv row = [Q(1024) | K(1024) | V(1024)] bf16.
// scores[h][g] = sum_d q[h,d] k[g,d] / 8; softmax over g; out[h,d] = sum_g p v[g,d].
__global__ __launch_bounds__(256) void k_attention(const unsigned short* __restrict__ qkv,
                                                   unsigned short* __restrict__ aout){
  constexpr int STRIDE = 68;                 // fp32 row stride per head (pad: 2-way max)
  constexpr int MATSZ  = 16 * STRIDE;        // 1088
  constexpr int PER    = 3 * MATSZ + 16 * 17; // 3536 floats / wave
  __shared__ float smem[4 * PER];

  const int lane = threadIdx.x & 63;
  const int wave = threadIdx.x >> 6;
  const int pos  = blockIdx.x * 4 + wave;

  float* base = smem + wave * PER;
  float* qf = base;
  float* kf = base + MATSZ;
  float* vf = base + 2 * MATSZ;
  float* pp = base + 3 * MATSZ;

  // stage q,k,v -> fp32 LDS (padded). 3072 bf16 per position, 48 per lane.
  const unsigned short* src = qkv + (size_t)pos * 3072;
  #pragma unroll
  for (int i = 0; i < 6; i++){
    int e = (i * 64 + lane) * 8;             // element offset in [0,3072), 16B aligned
    int mat = e >> 10, em = e & 1023;
    int h = em >> 6, d = em & 63;
    uint4 u = *(const uint4*)(src + e);
    const unsigned short* us = (const unsigned short*)&u;
    float* dst = base + mat * MATSZ + h * STRIDE + d;
    #pragma unroll
    for (int t = 0; t < 8; t++) dst[t] = bf2f(us[t]);
  }
  __syncthreads();

  const int h  = lane >> 2;          // head (query)
  const int gq = lane & 3;           // this lane covers g = gq*4 .. gq*4+3
  float s[4] = {0.f, 0.f, 0.f, 0.f};
  #pragma unroll
  for (int d4 = 0; d4 < 16; d4++){
    float4 qv = *(const float4*)(qf + h * STRIDE + d4 * 4);
    #pragma unroll
    for (int jj = 0; jj < 4; jj++){
      float4 kv = *(const float4*)(kf + (gq * 4 + jj) * STRIDE + d4 * 4);
      s[jj] += qv.x * kv.x + qv.y * kv.y + qv.z * kv.z + qv.w * kv.w;
    }
  }
  #pragma unroll
  for (int jj = 0; jj < 4; jj++) s[jj] *= 0.125f;

  float m = fmaxf(fmaxf(s[0], s[1]), fmaxf(s[2], s[3]));
  m = fmaxf(m, __shfl_xor(m, 1));
  m = fmaxf(m, __shfl_xor(m, 2));
  float e0 = __expf(s[0] - m), e1 = __expf(s[1] - m);
  float e2 = __expf(s[2] - m), e3 = __expf(s[3] - m);
  float sum = e0 + e1 + e2 + e3;
  sum += __shfl_xor(sum, 1);
  sum += __shfl_xor(sum, 2);
  float inv = 1.0f / sum;
  pp[h * 17 + gq * 4 + 0] = e0 * inv;
  pp[h * 17 + gq * 4 + 1] = e1 * inv;
  pp[h * 17 + gq * 4 + 2] = e2 * inv;
  pp[h * 17 + gq * 4 + 3] = e3 * inv;
  __syncthreads();

  // PV: lane covers out[h][dbase .. dbase+15]
  const int dbase = (lane & 3) * 16;
  float4 o0 = {0,0,0,0}, o1 = {0,0,0,0}, o2 = {0,0,0,0}, o3 = {0,0,0,0};
  #pragma unroll
  for (int g = 0; g < 16; g++){
    float p = pp[h * 17 + g];
    const float* vb = vf + g * STRIDE + dbase;
    float4 v0 = *(const float4*)(vb);
    float4 v1 = *(const float4*)(vb + 4);
    float4 v2 = *(const float4*)(vb + 8);
    float4 v3 = *(const float4*)(vb + 12);
    o0.x += p * v0.x; o0.y += p * v0.y; o0.z += p * v0.z; o0.w += p * v0.w;
    o1.x += p * v1.x; o1.y += p * v1.y; o1.z += p * v1.z; o1.w += p * v1.w;
    o2.x += p * v2.x; o2.y += p * v2.y; o2.z += p * v2.z; o2.w += p * v2.w;
    o3.x += p * v3.x; o3.y += p * v3.y; o3.z += p * v3.z; o3.w += p * v3.w;
  }
  unsigned short* dst = aout + (size_t)pos * 1024 + h * 64 + dbase;
  ushort4 r;
  r.x = f2bf_bits(o0.x); r.y = f2bf_bits(o0.y); r.z = f2bf_bits(o0.z); r.w = f2bf_bits(o0.w);
  ((ushort4*)dst)[0] = r;
  r.x = f2bf_bits(o1.x); r.y = f2bf_bits(o1.y); r.z = f2bf_bits(o1.z); r.w = f2bf_bits(o1.w);
  ((ushort4*)dst)[1] = r;
  r.x = f2bf_bits(o2.x); r.y = f2bf_bits(o2.y); r.z = f2bf_bits(o2.z); r.w = f2bf_bits(o2.w);
  ((ushort4*)dst)[2] = r;
  r.x = f2bf_bits(o3.x); r.y = f2bf_bits(o3.y); r.z = f2bf_bits(o3.z); r.w = f2bf_bits(o3.w);
  ((ushort4*)dst)[3] = r;
}

// ---------- in-place LayerNorm over rows of 1024 fp32 ----------
__global__ __launch_bounds__(256) void k_ln(float* __restrict__ out,
                                            const float* __restrict__ gamma,
                                            const float* __restrict__ beta){
  __shared__ float red[8];
  int tid = threadIdx.x;
  float4* rowp = (float4*)(out + (size_t)blockIdx.x * 1024);
  float4 v = rowp[tid];
  float s  = v.x + v.y + v.z + v.w;
  float ss = v.x * v.x + v.y * v.y + v.z * v.z + v.w * v.w;
  #pragma unroll
  for (int off = 32; off > 0; off >>= 1){
    s  += __shfl_down(s, off);
    ss += __shfl_down(ss, off);
  }
  if ((tid & 63) == 0){ red[tid >> 6] = s; red[4 + (tid >> 6)] = ss; }
  __syncthreads();
  float S  = red[0] + red[1] + red[2] + red[3];
  float SS = red[4] + red[5] + red[6] + red[7];
  float mean = S * (1.0f / 1024.0f);
  float var  = SS * (1.0f / 1024.0f) - mean * mean;
  float rstd = rsqrtf(var + 1e-5f);
  float4 g = ((const float4*)gamma)[tid];
  float4 b = ((const float4*)beta)[tid];
  v.x = (v.x - mean) * rstd * g.x + b.x;
  v.y = (v.y - mean) * rstd * g.y + b.y;
  v.z = (v.z - mean) * rstd * g.z + b.z;
  v.w = (v.w - mean) * rstd * g.w + b.w;
  rowp[tid] = v;
}

extern "C" void kernel_launch(void* const* d_in, const int* in_sizes, int n_in,
                              void* d_out, int out_size, void* d_ws, size_t ws_size,
                              hipStream_t stream){
  const float* x     = (const float*)d_in[0];
  const float* Wq    = (const float*)d_in[1];
  const float* bq    = (const float*)d_in[2];
  const float* Wk    = (const float*)d_in[3];
  const float* bk    = (const float*)d_in[4];
  const float* Wv    = (const float*)d_in[5];
  const float* bv    = (const float*)d_in[6];
  const float* Wo    = (const float*)d_in[7];
  const float* bo    = (const float*)d_in[8];
  const float* gamma = (const float*)d_in[9];
  const float* beta  = (const float*)d_in[10];
  float* out = (float*)d_out;

  // workspace layout (bytes):
  //   [0, 6291456)            Wqkv^T bf16 (3072 x 1024)
  //   [6291456, 8388608)      Wo^T bf16  (1024 x 1024)
  //   [8388608, 75497472)     xb bf16 (32768 x 1024); reused as attn-out after GEMM1
  //   [75497472, 276824064)   qkv bf16 (32768 x 3072)
  char* ws = (char*)d_ws;
  unsigned short* Wqkv_t = (unsigned short*)ws;
  unsigned short* Wo_t   = (unsigned short*)(ws + 6291456);
  unsigned short* xb     = (unsigned short*)(ws + 8388608);
  unsigned short* qkv    = (unsigned short*)(ws + 75497472);
  unsigned short* aout   = xb;   // reuse: xb consumed by GEMM1 before attention writes

  // 1) x -> bf16
  k_convert_bf16<<<32768, 256, 0, stream>>>(x, xb, (MM * FFD) / 4);

  // 2) weight transposes (fp32 KxN -> bf16 NxK)
  dim3 tb(32, 8), tg(32, 32);
  k_transpose_bf16<<<tg, tb, 0, stream>>>(Wq, Wqkv_t,                1024, 1024);
  k_transpose_bf16<<<tg, tb, 0, stream>>>(Wk, Wqkv_t + 1024 * 1024,  1024, 1024);
  k_transpose_bf16<<<tg, tb, 0, stream>>>(Wv, Wqkv_t + 2048 * 1024,  1024, 1024);
  k_transpose_bf16<<<tg, tb, 0, stream>>>(Wo, Wo_t,                  1024, 1024);

  // 3) QKV GEMM: (32768 x 1024) @ (1024 x 3072) -> bf16
  k_gemm_bt<true><<<dim3(NQKV / 128, MM / 128), 256, 0, stream>>>(
      xb, Wqkv_t, bq, bk, bv, qkv, MM, NQKV, FFD);

  // 4) per-position head attention
  k_attention<<<MM / 4, 256, 0, stream>>>(qkv, aout);

  // 5) output GEMM: (32768 x 1024) @ (1024 x 1024) + bo -> fp32 d_out
  k_gemm_bt<false><<<dim3(FFD / 128, MM / 128), 256, 0, stream>>>(
      aout, Wo_t, bo, bo, bo, out, MM, FFD, FFD);

  // 6) LayerNorm in-place
  k_ln<<<MM, 256, 0, stream>>>(out, gamma, beta);
}

// Round 2
// 704.052 us; speedup vs baseline: 1.0338x; 1.0338x over previous
//
#include <hip/hip_runtime.h>
#include <hip/hip_bf16.h>
#include <stdint.h>

// Problem constants
#define MM   32768   // B*S
#define FFD  1024    // F
#define NQKV 3072    // 3*F

typedef __bf16 bf16x8 __attribute__((ext_vector_type(8)));
typedef float  f32x4  __attribute__((ext_vector_type(4)));

__device__ __forceinline__ unsigned short f2bf_bits(float f){
  __hip_bfloat16 h = __float2bfloat16(f);
  unsigned short u;
  __builtin_memcpy(&u, &h, 2);
  return u;
}

__device__ __forceinline__ void gld16(const void* g, void* l){
  const unsigned int* gu = (const unsigned int*)g;
  unsigned int* lu = (unsigned int*)l;
  __builtin_amdgcn_global_load_lds(
      (const __attribute__((address_space(1))) unsigned int*)gu,
      (__attribute__((address_space(3))) unsigned int*)lu,
      16, 0, 0);
}

// ---------- convert fp32 -> bf16, 4 elems/thread ----------
__global__ __launch_bounds__(256) void k_convert_bf16(const float* __restrict__ in,
                                                      unsigned short* __restrict__ out,
                                                      int n4){
  int i = blockIdx.x * 256 + threadIdx.x;
  if (i >= n4) return;
  float4 v = ((const float4*)in)[i];
  ushort4 r;
  r.x = f2bf_bits(v.x); r.y = f2bf_bits(v.y);
  r.z = f2bf_bits(v.z); r.w = f2bf_bits(v.w);
  ((ushort4*)out)[i] = r;
}

// ---------- transpose-convert: out(N x K bf16) = in(K x N fp32)^T ----------
__global__ __launch_bounds__(256) void k_transpose_bf16(const float* __restrict__ in,
                                                        unsigned short* __restrict__ out,
                                                        int rows, int cols){
  __shared__ float tile[32][33];
  int bc = blockIdx.x * 32, br = blockIdx.y * 32;
  int tx = threadIdx.x, ty = threadIdx.y;
  #pragma unroll
  for (int j = 0; j < 32; j += 8)
    tile[ty + j][tx] = in[(size_t)(br + ty + j) * cols + bc + tx];
  __syncthreads();
  #pragma unroll
  for (int j = 0; j < 32; j += 8)
    out[(size_t)(bc + ty + j) * rows + br + tx] = f2bf_bits(tile[tx][ty + j]);
}

// ---------- bf16 MFMA GEMM: C(MxN) = A(MxK) * Bt(NxK)^T + bias ----------
// 128x128 block tile, 256 threads (4 waves in 2x2), 16x16x32 MFMA, BK=64.
// LDS holds two consecutive [128][32] half-buffers per operand (the verified
// BK=32 staging/banking pattern, x2) so one barrier pair covers 32 MFMAs/wave.
template <bool BF16OUT>
__global__ __launch_bounds__(256) void k_gemm_bt(
    const unsigned short* __restrict__ A,
    const unsigned short* __restrict__ Bt,
    const float* __restrict__ b0, const float* __restrict__ b1, const float* __restrict__ b2,
    void* __restrict__ Cout, int M, int N, int K)
{
  __shared__ unsigned short As[128 * 64];
  __shared__ unsigned short Bs[128 * 64];

  const int tid  = threadIdx.x;
  const int lane = tid & 63;
  const int wave = tid >> 6;
  const int wr = wave >> 1, wc = wave & 1;
  const int quad = lane >> 4, lrow = lane & 15;

  const long rowBase = (long)blockIdx.y * 128;
  const long colBase = (long)blockIdx.x * 128;

  f32x4 acc[4][4];
  #pragma unroll
  for (int i = 0; i < 4; i++)
    #pragma unroll
    for (int j = 0; j < 4; j++)
      acc[i][j] = (f32x4){0.f, 0.f, 0.f, 0.f};

  // staging: thread t covers (row = t>>2, kchunk = t&3) within a [64][32] pass
  const unsigned short* ga = A  + (rowBase + (tid >> 2)) * (long)K + (tid & 3) * 8;
  const unsigned short* gb = Bt + (colBase + (tid >> 2)) * (long)K + (tid & 3) * 8;
  unsigned short* la = As + tid * 8;
  unsigned short* lb = Bs + tid * 8;
  const long rstep = 64L * K;  // 64 rows, in elements

  const int nk = K >> 6;
  for (int kt = 0; kt < nk; kt++){
    __syncthreads();                 // previous tile's reads done
    // half 0 (k offset +0), half 1 (k offset +32)
    gld16(ga,               la);
    gld16(ga + rstep,       la + 2048);
    gld16(ga + 32,          la + 4096);
    gld16(ga + 32 + rstep,  la + 6144);
    gld16(gb,               lb);
    gld16(gb + rstep,       lb + 2048);
    gld16(gb + 32,          lb + 4096);
    gld16(gb + 32 + rstep,  lb + 6144);
    __syncthreads();                 // loads landed (vmcnt drain at barrier)

    #pragma unroll
    for (int kk = 0; kk < 2; kk++){
      const unsigned short* Ah = As + kk * 4096;
      const unsigned short* Bh = Bs + kk * 4096;
      bf16x8 af[4], bfr[4];
      #pragma unroll
      for (int i = 0; i < 4; i++)
        af[i]  = *(const bf16x8*)(Ah + (wr * 64 + i * 16 + lrow) * 32 + quad * 8);
      #pragma unroll
      for (int j = 0; j < 4; j++)
        bfr[j] = *(const bf16x8*)(Bh + (wc * 64 + j * 16 + lrow) * 32 + quad * 8);

      #pragma unroll
      for (int i = 0; i < 4; i++)
        #pragma unroll
        for (int j = 0; j < 4; j++)
          acc[i][j] = __builtin_amdgcn_mfma_f32_16x16x32_bf16(af[i], bfr[j], acc[i][j], 0, 0, 0);
    }

    ga += 64; gb += 64;
  }

  // epilogue: C/D layout col = lane&15, row = quad*4 + r
  #pragma unroll
  for (int j = 0; j < 4; j++){
    long col = colBase + wc * 64 + j * 16 + lrow;
    const float* bp = (col < 1024) ? b0 : ((col < 2048) ? b1 : b2);
    float bias = bp[col & 1023];
    #pragma unroll
    for (int i = 0; i < 4; i++){
      long row0 = rowBase + wr * 64 + i * 16 + quad * 4;
      #pragma unroll
      for (int r = 0; r < 4; r++){
        float v = acc[i][j][r] + bias;
        if constexpr (BF16OUT)
          ((unsigned short*)Cout)[(row0 + r) * (long)N + col] = f2bf_bits(v);
        else
          ((float*)Cout)[(row0 + r) * (long)N + col] = v;
      }
    }
  }
}

// ---------- per-position head-attention via MFMA ----------
// One wave per position (4/block). qkv row = [Q(1024)|K(1024)|V(1024)] bf16,
// each matrix [head][d] 16x64. scores = Q K^T / 8 (2x mfma 16x16x32),
// softmax over key-head axis, out = P V (4x mfma with K=32, upper 16 zero-pad).
// LDS per wave (bf16 elems): Q[16][72], K[16][72], Vt[64][40] (g padded to 32,
// rows 16-31 zeroed), P[16][40] (cols 16-31 zeroed). Q region reused for out.
__global__ __launch_bounds__(256) void k_attention(const unsigned short* __restrict__ qkv,
                                                   unsigned short* __restrict__ aout){
  constexpr int QOFF = 0;            // [16][72] = 1152
  constexpr int KOFF = 1152;         // [16][72] = 1152
  constexpr int VOFF = 2304;         // [64][40] = 2560
  constexpr int POFF = 4864;         // [16][40] = 640
  constexpr int PER  = 5504;         // ushorts per wave
  __shared__ unsigned short smem[4 * PER];

  const int lane = threadIdx.x & 63;
  const int wave = threadIdx.x >> 6;
  const int pos  = blockIdx.x * 4 + wave;
  const int quad = lane >> 4, lidx = lane & 15;

  unsigned short* base = smem + wave * PER;
  unsigned short* Qb = base + QOFF;
  unsigned short* Kb = base + KOFF;
  unsigned short* Vt = base + VOFF;
  unsigned short* Pb = base + POFF;

  // zero pads: Vt rows g in [16,32) for all d; P cols [16,32)
  {
    // Vt: lane covers d = lane, 16 ushorts at [d][16..32) -> two uint4
    uint4 z = {0u, 0u, 0u, 0u};
    *(uint4*)(Vt + lane * 40 + 16) = z;
    *(uint4*)(Vt + lane * 40 + 24) = z;
    // P: lane covers row lane>>2, cols 16 + (lane&3)*4 -> uint2 (4 ushorts)
    *(uint2*)(Pb + (lane >> 2) * 40 + 16 + (lane & 3) * 4) = make_uint2(0u, 0u);
  }

  // stage: 384 uint4 chunks of 8 bf16; lane takes chunks lane + 64*i
  const unsigned short* src = qkv + (size_t)pos * 3072;
  #pragma unroll
  for (int i = 0; i < 6; i++){
    int c = i * 64 + lane;                 // chunk in [0,384)
    uint4 u = *(const uint4*)(src + c * 8);
    if (i < 4){
      // Q (c<128) or K: [h][d] row-major, h = (c&127)>>3, d0 = (c&7)*8
      unsigned short* mb = (c < 128) ? Qb : Kb;
      int cc = c & 127;
      *(uint4*)(mb + (cc >> 3) * 72 + (cc & 7) * 8) = u;
    } else {
      // V: g = cv>>3, d0 = (cv&7)*8; scatter into Vt[d][g]
      int cv = c - 256;
      int g = cv >> 3, d0 = (cv & 7) * 8;
      const unsigned short* us = (const unsigned short*)&u;
      #pragma unroll
      for (int t = 0; t < 8; t++) Vt[(d0 + t) * 40 + g] = us[t];
    }
  }
  __syncthreads();

  // QK^T: D(16x16) over d-halves
  f32x4 s = (f32x4){0.f, 0.f, 0.f, 0.f};
  #pragma unroll
  for (int kk = 0; kk < 2; kk++){
    bf16x8 a = *(const bf16x8*)(Qb + lidx * 72 + kk * 32 + quad * 8);
    bf16x8 b = *(const bf16x8*)(Kb + lidx * 72 + kk * 32 + quad * 8);
    s = __builtin_amdgcn_mfma_f32_16x16x32_bf16(a, b, s, 0, 0, 0);
  }

  // softmax over col axis (g = lane&15), per row r: row = quad*4 + r
  #pragma unroll
  for (int r = 0; r < 4; r++){
    float v = s[r] * 0.125f;
    float m = v;
    m = fmaxf(m, __shfl_xor(m, 1));
    m = fmaxf(m, __shfl_xor(m, 2));
    m = fmaxf(m, __shfl_xor(m, 4));
    m = fmaxf(m, __shfl_xor(m, 8));
    float e = __expf(v - m);
    float sum = e;
    sum += __shfl_xor(sum, 1);
    sum += __shfl_xor(sum, 2);
    sum += __shfl_xor(sum, 4);
    sum += __shfl_xor(sum, 8);
    float p = e / sum;
    Pb[(quad * 4 + r) * 40 + lidx] = f2bf_bits(p);
  }
  __syncthreads();

  // PV: out(16x64) in 4 column chunks of 16
  f32x4 o[4];
  #pragma unroll
  for (int n4 = 0; n4 < 4; n4++){
    bf16x8 a = *(const bf16x8*)(Pb + lidx * 40 + quad * 8);
    bf16x8 b = *(const bf16x8*)(Vt + (n4 * 16 + lidx) * 40 + quad * 8);
    o[n4] = __builtin_amdgcn_mfma_f32_16x16x32_bf16(a, b, (f32x4){0.f,0.f,0.f,0.f}, 0, 0, 0);
  }

  // stage out into Qb region [16][72] for coalesced global write
  #pragma unroll
  for (int n4 = 0; n4 < 4; n4++)
    #pragma unroll
    for (int r = 0; r < 4; r++)
      Qb[(quad * 4 + r) * 72 + n4 * 16 + lidx] = f2bf_bits(o[n4][r]);
  __syncthreads();

  // copy out: 128 chunks of 8 elems; lane takes chunks 2*lane, 2*lane+1
  unsigned short* dst = aout + (size_t)pos * 1024;
  #pragma unroll
  for (int t = 0; t < 2; t++){
    int j = lane * 2 + t;
    int h = j >> 3, dc = j & 7;
    uint4 u = *(const uint4*)(Qb + h * 72 + dc * 8);
    *(uint4*)(dst + j * 8) = u;
  }
}

// ---------- in-place LayerNorm over rows of 1024 fp32 ----------
__global__ __launch_bounds__(256) void k_ln(float* __restrict__ out,
                                            const float* __restrict__ gamma,
                                            const float* __restrict__ beta){
  __shared__ float red[8];
  int tid = threadIdx.x;
  float4* rowp = (float4*)(out + (size_t)blockIdx.x * 1024);
  float4 v = rowp[tid];
  float s  = v.x + v.y + v.z + v.w;
  float ss = v.x * v.x + v.y * v.y + v.z * v.z + v.w * v.w;
  #pragma unroll
  for (int off = 32; off > 0; off >>= 1){
    s  += __shfl_down(s, off);
    ss += __shfl_down(ss, off);
  }
  if ((tid & 63) == 0){ red[tid >> 6] = s; red[4 + (tid >> 6)] = ss; }
  __syncthreads();
  float S  = red[0] + red[1] + red[2] + red[3];
  float SS = red[4] + red[5] + red[6] + red[7];
  float mean = S * (1.0f / 1024.0f);
  float var  = SS * (1.0f / 1024.0f) - mean * mean;
  float rstd = rsqrtf(var + 1e-5f);
  float4 g = ((const float4*)gamma)[tid];
  float4 b = ((const float4*)beta)[tid];
  v.x = (v.x - mean) * rstd * g.x + b.x;
  v.y = (v.y - mean) * rstd * g.y + b.y;
  v.z = (v.z - mean) * rstd * g.z + b.z;
  v.w = (v.w - mean) * rstd * g.w + b.w;
  rowp[tid] = v;
}

extern "C" void kernel_launch(void* const* d_in, const int* in_sizes, int n_in,
                              void* d_out, int out_size, void* d_ws, size_t ws_size,
                              hipStream_t stream){
  const float* x     = (const float*)d_in[0];
  const float* Wq    = (const float*)d_in[1];
  const float* bq    = (const float*)d_in[2];
  const float* Wk    = (const float*)d_in[3];
  const float* bk    = (const float*)d_in[4];
  const float* Wv    = (const float*)d_in[5];
  const float* bv    = (const float*)d_in[6];
  const float* Wo    = (const float*)d_in[7];
  const float* bo    = (const float*)d_in[8];
  const float* gamma = (const float*)d_in[9];
  const float* beta  = (const float*)d_in[10];
  float* out = (float*)d_out;

  // workspace layout (bytes):
  //   [0, 6291456)            Wqkv^T bf16 (3072 x 1024)
  //   [6291456, 8388608)      Wo^T bf16  (1024 x 1024)
  //   [8388608, 75497472)     xb bf16 (32768 x 1024); reused as attn-out after GEMM1
  //   [75497472, 276824064)   qkv bf16 (32768 x 3072)
  char* ws = (char*)d_ws;
  unsigned short* Wqkv_t = (unsigned short*)ws;
  unsigned short* Wo_t   = (unsigned short*)(ws + 6291456);
  unsigned short* xb     = (unsigned short*)(ws + 8388608);
  unsigned short* qkv    = (unsigned short*)(ws + 75497472);
  unsigned short* aout   = xb;   // reuse: xb consumed by GEMM1 before attention writes

  // 1) x -> bf16
  k_convert_bf16<<<32768, 256, 0, stream>>>(x, xb, (MM * FFD) / 4);

  // 2) weight transposes (fp32 KxN -> bf16 NxK)
  dim3 tb(32, 8), tg(32, 32);
  k_transpose_bf16<<<tg, tb, 0, stream>>>(Wq, Wqkv_t,                1024, 1024);
  k_transpose_bf16<<<tg, tb, 0, stream>>>(Wk, Wqkv_t + 1024 * 1024,  1024, 1024);
  k_transpose_bf16<<<tg, tb, 0, stream>>>(Wv, Wqkv_t + 2048 * 1024,  1024, 1024);
  k_transpose_bf16<<<tg, tb, 0, stream>>>(Wo, Wo_t,                  1024, 1024);

  // 3) QKV GEMM: (32768 x 1024) @ (1024 x 3072) -> bf16
  k_gemm_bt<true><<<dim3(NQKV / 128, MM / 128), 256, 0, stream>>>(
      xb, Wqkv_t, bq, bk, bv, qkv, MM, NQKV, FFD);

  // 4) per-position head attention (MFMA)
  k_attention<<<MM / 4, 256, 0, stream>>>(qkv, aout);

  // 5) output GEMM: (32768 x 1024) @ (1024 x 1024) + bo -> fp32 d_out
  k_gemm_bt<false><<<dim3(FFD / 128, MM / 128), 256, 0, stream>>>(
      aout, Wo_t, bo, bo, bo, out, MM, FFD, FFD);

  // 6) LayerNorm in-place
  k_ln<<<MM, 256, 0, stream>>>(out, gamma, beta);
}